// Round 8
// baseline (696.685 us; speedup 1.0000x reference)
//
#include <hip/hip_runtime.h>
#include <hip/hip_cooperative_groups.h>

namespace cg = cooperative_groups;

#define N_NODES 50000
#define N_EDGES 800000
#define IN_DIM 128
#define HID_DIM 256
#define OUT_DIM 2

typedef __attribute__((ext_vector_type(8))) short bh8;   // 8 bf16 (A/B frag)
typedef __attribute__((ext_vector_type(4))) float f4;    // C/D frag

__device__ inline unsigned bf16rne(float f) {
    unsigned u = __float_as_uint(f);
    return (u + 0x7fffu + ((u >> 16) & 1u)) >> 16;
}

// ======================= phase bodies (shared by both paths) ================

__device__ __forceinline__ void ph_prep(int gtid, int gsz,
    const float* __restrict__ x, const float* __restrict__ W1,
    unsigned* __restrict__ xb, unsigned* __restrict__ W1p, int* __restrict__ deg)
{
    for (int i = gtid; i < 3200000; i += gsz) {          // all of x (3.2M float2)
        float2 v = ((const float2*)x)[i];
        xb[i] = (bf16rne(v.y) << 16) | bf16rne(v.x);
    }
    for (int j = gtid; j < 16384; j += gsz) {            // W1 -> B-frag pack
        int d = j & 3, l = (j >> 2) & 63, s = (j >> 8) & 3, t = j >> 10;
        int k = 32 * s + 8 * (l >> 4) + 2 * d;
        int n = 16 * t + (l & 15);
        W1p[j] = (bf16rne(W1[(size_t)(k + 1) * HID_DIM + n]) << 16)
               |  bf16rne(W1[(size_t)k * HID_DIM + n]);
    }
    for (int i = gtid; i < N_NODES; i += gsz) deg[i] = 0;
}

__device__ __forceinline__ void ph_hist(int gtid, int gsz,
    const int* __restrict__ ei, int* __restrict__ deg)
{
    for (int e = gtid; e < N_EDGES; e += gsz)
        atomicAdd(&deg[ei[N_EDGES + e]], 1);
}

// chunk-local exclusive scan; requires full 256-thread block, bid < 196
__device__ __forceinline__ void ph_scan1(int bid, int tid, int lane, int wv,
    const int* __restrict__ deg, int* __restrict__ row_ptr,
    int* __restrict__ partials, int* s_red)
{
    int i = bid * 256 + tid;
    int v = (i < N_NODES) ? deg[i] : 0;
    int s = v;
#pragma unroll
    for (int off = 1; off < 64; off <<= 1) {
        int t = __shfl_up(s, off, 64);
        if (lane >= off) s += t;
    }
    if (lane == 63) s_red[wv] = s;
    __syncthreads();
    int wexcl = 0;
    for (int w = 0; w < wv; w++) wexcl += s_red[w];
    if (i < N_NODES) row_ptr[i] = wexcl + s - v;
    if (tid == 0) partials[bid] = s_red[0] + s_red[1] + s_red[2] + s_red[3];
    __syncthreads();                                      // s_red reused later
}

__device__ __forceinline__ void ph_scan2(int bid, int tid, int lane, int wv,
    int* __restrict__ row_ptr, const int* __restrict__ partials,
    int* __restrict__ cursor, int* s_red)
{
    int v = (tid < bid) ? partials[tid] : 0;              // bid <= 195 < 256
#pragma unroll
    for (int off = 1; off < 64; off <<= 1) v += __shfl_xor(v, off, 64);
    if (lane == 0) s_red[wv] = v;
    __syncthreads();
    int offset = s_red[0] + s_red[1] + s_red[2] + s_red[3];
    int i = bid * 256 + tid;
    if (i < N_NODES) {
        int r = row_ptr[i] + offset;
        row_ptr[i] = r;
        cursor[i]  = r;
    }
    __syncthreads();
}

__device__ __forceinline__ void ph_reorder(int gtid, int gsz,
    const int* __restrict__ ei, int* __restrict__ cursor, int* __restrict__ csr_src)
{
    for (int e = gtid; e < N_EDGES; e += gsz) {
        int dst = ei[N_EDGES + e];
        int pos = atomicAdd(&cursor[dst], 1);
        csr_src[pos] = ei[e];
    }
}

// one 16-node tile: gather + MFMA GEMM1 + epilogue (verified in R6)
__device__ __forceinline__ void ph_gin1(int node0, int lane, unsigned* zrow,
    const float* __restrict__ x, const unsigned* __restrict__ xb,
    const int* __restrict__ row_ptr, const int* __restrict__ csr_src,
    const unsigned* __restrict__ W1p, const float* __restrict__ b1,
    const float* __restrict__ W2, const float* __restrict__ b2,
    float e1, float e2, float* __restrict__ p, float* __restrict__ out)
{
    for (int nn = 0; nn < 16; nn++) {
        int node = node0 + nn;
        float ax = 0.f, ay = 0.f;
        int beg = row_ptr[node], end = row_ptr[node + 1];
        for (int bb = beg; bb < end; bb += 64) {
            int cnt = min(64, end - bb);
            int srcs = csr_src[bb + ((lane < cnt) ? lane : 0)];
            for (int j0 = 0; j0 < cnt; j0 += 16) {
                unsigned u[16];
#pragma unroll
                for (int g = 0; g < 16; g++) {
                    int idx = j0 + g;
                    int sq = __shfl(srcs, (idx < cnt) ? idx : 0, 64);
                    u[g] = xb[(size_t)sq * 64 + lane];
                }
#pragma unroll
                for (int g = 0; g < 16; g++) {
                    if (j0 + g < cnt) {
                        ax += __uint_as_float(u[g] << 16);
                        ay += __uint_as_float(u[g] & 0xffff0000u);
                    }
                }
            }
        }
        float2 xv = *(const float2*)(x + (size_t)node * IN_DIM + 2 * lane);
        ax = fmaf(e1, xv.x, ax);
        ay = fmaf(e1, xv.y, ay);
        zrow[nn * 68 + lane] = (bf16rne(ay) << 16) | bf16rne(ax);
    }
    const int q = lane >> 4, c = lane & 15;
    bh8 afrag[4];
#pragma unroll
    for (int s = 0; s < 4; s++)
        afrag[s] = *(const bh8*)&zrow[c * 68 + 16 * s + 4 * q];

    f4 acc[16];
#pragma unroll
    for (int t = 0; t < 16; t++) acc[t] = (f4){0.f, 0.f, 0.f, 0.f};
#pragma unroll
    for (int t = 0; t < 16; t++) {
#pragma unroll
        for (int s = 0; s < 4; s++) {
            bh8 bfrag = *(const bh8*)(W1p + ((size_t)(t * 4 + s) * 64 + lane) * 4);
            acc[t] = __builtin_amdgcn_mfma_f32_16x16x32_bf16(afrag[s], bfrag, acc[t], 0, 0, 0);
        }
    }
    float pxr[4] = {0.f, 0.f, 0.f, 0.f};
    float pyr[4] = {0.f, 0.f, 0.f, 0.f};
#pragma unroll
    for (int t = 0; t < 16; t++) {
        int n = 16 * t + c;
        float bb = b1[n];
        float2 w2 = *(const float2*)(W2 + (size_t)n * OUT_DIM);
#pragma unroll
        for (int r = 0; r < 4; r++) {
            float h = fmaxf(acc[t][r] + bb, 0.f);
            pxr[r] = fmaf(h, w2.x, pxr[r]);
            pyr[r] = fmaf(h, w2.y, pyr[r]);
        }
    }
#pragma unroll
    for (int off = 1; off < 16; off <<= 1) {
#pragma unroll
        for (int r = 0; r < 4; r++) {
            pxr[r] += __shfl_xor(pxr[r], off, 64);
            pyr[r] += __shfl_xor(pyr[r], off, 64);
        }
    }
    if (c == 0) {
        float2 b2v = *(const float2*)b2;
#pragma unroll
        for (int r = 0; r < 4; r++) {
            int node = node0 + q * 4 + r;
            *(float2*)(p + (size_t)node * OUT_DIM) = make_float2(pxr[r], pyr[r]);
            float2 o;
            o.x = fmaf(e2, pxr[r], b2v.x);
            o.y = fmaf(e2, pyr[r], b2v.y);
            *(float2*)(out + (size_t)node * OUT_DIM) = o;
        }
    }
}

__device__ __forceinline__ void ph_out(int node, int l,
    const int* __restrict__ row_ptr, const int* __restrict__ csr_src,
    const float* __restrict__ p, float* __restrict__ out)
{
    float sx = 0.f, sy = 0.f;
    if (node < N_NODES) {
        int beg = row_ptr[node], end = row_ptr[node + 1];
        for (int j = beg + l; j < end; j += 8) {
            int src = csr_src[j];
            float2 v = *(const float2*)(p + (size_t)src * OUT_DIM);
            sx += v.x; sy += v.y;
        }
    }
#pragma unroll
    for (int off = 1; off <= 4; off <<= 1) {
        sx += __shfl_xor(sx, off, 64);
        sy += __shfl_xor(sy, off, 64);
    }
    if (l == 0 && node < N_NODES) {
        float2 o = *(const float2*)(out + (size_t)node * OUT_DIM);
        o.x += sx; o.y += sy;
        *(float2*)(out + (size_t)node * OUT_DIM) = o;
    }
}

// ======================= path 1: single cooperative kernel ==================

__global__ __launch_bounds__(256, 4) void k_all(
    const float* x, const int* ei, const float* W1, const float* b1,
    const float* W2, const float* b2, const float* eps1p, const float* eps2p,
    float* out, int* deg, int* row_ptr, int* cursor, int* csr_src,
    float* p, unsigned* xb, unsigned* W1p, int* partials)
{
    __shared__ unsigned z16[4][16 * 68];
    __shared__ int s_red[4];
    cg::grid_group grid = cg::this_grid();
    const int tid = threadIdx.x, lane = tid & 63, wv = tid >> 6;
    const int bid = blockIdx.x;
    const int gsz = gridDim.x * 256;
    const int gtid = bid * 256 + tid;

    ph_prep(gtid, gsz, x, W1, xb, W1p, deg);
    grid.sync();
    ph_hist(gtid, gsz, ei, deg);
    grid.sync();
    if (bid < 196) ph_scan1(bid, tid, lane, wv, deg, row_ptr, partials, s_red);
    grid.sync();
    if (bid < 196) ph_scan2(bid, tid, lane, wv, row_ptr, partials, cursor, s_red);
    if (gtid == 0) row_ptr[N_NODES] = N_EDGES;
    grid.sync();
    ph_reorder(gtid, gsz, ei, cursor, csr_src);
    grid.sync();
    {
        const float e1 = 1.0f + eps1p[0];
        const float e2 = 1.0f + eps2p[0];
        for (int wu = bid * 4 + wv; wu < 3125; wu += gridDim.x * 4)
            ph_gin1(wu * 16, lane, &z16[wv][0], x, xb, row_ptr, csr_src,
                    W1p, b1, W2, b2, e1, e2, p, out);
    }
    grid.sync();
    for (int base = bid * 32; base < N_NODES; base += gridDim.x * 32)
        ph_out(base + wv * 8 + (lane >> 3), lane & 7, row_ptr, csr_src, p, out);
}

// ======================= path 2: fallback multi-kernel ======================

__global__ __launch_bounds__(256) void f_prep(const float* x, const float* W1,
    unsigned* xb, unsigned* W1p, int* deg)
{ ph_prep(blockIdx.x * 256 + threadIdx.x, gridDim.x * 256, x, W1, xb, W1p, deg); }

__global__ __launch_bounds__(256) void f_hist(const int* ei, int* deg)
{ ph_hist(blockIdx.x * 256 + threadIdx.x, gridDim.x * 256, ei, deg); }

__global__ __launch_bounds__(256) void f_scan1(const int* deg, int* row_ptr, int* partials)
{
    __shared__ int s_red[4];
    int tid = threadIdx.x;
    ph_scan1(blockIdx.x, tid, tid & 63, tid >> 6, deg, row_ptr, partials, s_red);
}

__global__ __launch_bounds__(256) void f_scan2(int* row_ptr, const int* partials, int* cursor)
{
    __shared__ int s_red[4];
    int tid = threadIdx.x;
    ph_scan2(blockIdx.x, tid, tid & 63, tid >> 6, row_ptr, partials, cursor, s_red);
    if (blockIdx.x == 0 && tid == 0) row_ptr[N_NODES] = N_EDGES;
}

__global__ __launch_bounds__(256) void f_reorder(const int* ei, int* cursor, int* csr_src)
{ ph_reorder(blockIdx.x * 256 + threadIdx.x, gridDim.x * 256, ei, cursor, csr_src); }

__global__ __launch_bounds__(256) void f_gin1(
    const float* x, const unsigned* xb, const int* row_ptr, const int* csr_src,
    const unsigned* W1p, const float* b1, const float* W2, const float* b2,
    const float* eps1p, const float* eps2p, float* p, float* out)
{
    __shared__ unsigned z16[4][16 * 68];
    const int tid = threadIdx.x, lane = tid & 63, wv = tid >> 6;
    const float e1 = 1.0f + eps1p[0];
    const float e2 = 1.0f + eps2p[0];
    for (int wu = blockIdx.x * 4 + wv; wu < 3125; wu += gridDim.x * 4)
        ph_gin1(wu * 16, lane, &z16[wv][0], x, xb, row_ptr, csr_src,
                W1p, b1, W2, b2, e1, e2, p, out);
}

__global__ __launch_bounds__(256) void f_out(const int* row_ptr, const int* csr_src,
    const float* p, float* out)
{
    const int tid = threadIdx.x, lane = tid & 63, wv = tid >> 6;
    for (int base = blockIdx.x * 32; base < N_NODES; base += gridDim.x * 32)
        ph_out(base + wv * 8 + (lane >> 3), lane & 7, row_ptr, csr_src, p, out);
}

// ======================= host ==============================================

extern "C" void kernel_launch(void* const* d_in, const int* in_sizes, int n_in,
                              void* d_out, int out_size, void* d_ws, size_t ws_size,
                              hipStream_t stream)
{
    (void)in_sizes; (void)n_in; (void)out_size; (void)ws_size;
    const float* x    = (const float*)d_in[0];
    const int*   ei   = (const int*)d_in[1];
    const float* W1   = (const float*)d_in[2];
    const float* b1   = (const float*)d_in[3];
    const float* W2   = (const float*)d_in[4];
    const float* b2   = (const float*)d_in[5];
    const float* eps1 = (const float*)d_in[6];
    const float* eps2 = (const float*)d_in[7];
    float* out = (float*)d_out;

    int* deg      = (int*)d_ws;                       // 50048
    int* row_ptr  = deg + 50048;                      // 50056 (N_NODES+1)
    int* cursor   = row_ptr + 50056;                  // 50048
    int* csr_src  = cursor + 50048;                   // 800000
    float* p      = (float*)(csr_src + 800000);       // 100000
    unsigned* xb  = (unsigned*)(p + 100000);          // 3200000
    unsigned* W1p = xb + 3200000;                     // 16384
    int* partials = (int*)(W1p + 16384);              // 256

    // ---- try cooperative path, sized by queried occupancy ----
    int occ = 0;
    hipError_t qe = hipOccupancyMaxActiveBlocksPerMultiprocessor(&occ, k_all, 256, 0);
    int grid = occ * 256;                             // 256 CUs (MI355X)
    if (grid > 784) grid = 784;
    bool coop_ok = (qe == hipSuccess) && (grid >= 196);

    if (coop_ok) {
        void* args[] = {
            (void*)&x, (void*)&ei, (void*)&W1, (void*)&b1, (void*)&W2, (void*)&b2,
            (void*)&eps1, (void*)&eps2, (void*)&out,
            (void*)&deg, (void*)&row_ptr, (void*)&cursor, (void*)&csr_src,
            (void*)&p, (void*)&xb, (void*)&W1p, (void*)&partials
        };
        hipError_t le = hipLaunchCooperativeKernel(k_all, dim3(grid), dim3(256),
                                                   args, 0, stream);
        if (le == hipSuccess) return;
        coop_ok = false;
    }

    // ---- fallback: multi-kernel sequence (R6-equivalent, verified) ----
    f_prep<<<784, 256, 0, stream>>>(x, W1, xb, W1p, deg);
    f_hist<<<784, 256, 0, stream>>>(ei, deg);
    f_scan1<<<196, 256, 0, stream>>>(deg, row_ptr, partials);
    f_scan2<<<196, 256, 0, stream>>>(row_ptr, partials, cursor);
    f_reorder<<<784, 256, 0, stream>>>(ei, cursor, csr_src);
    f_gin1<<<784, 256, 0, stream>>>(x, xb, row_ptr, csr_src, W1p, b1, W2, b2,
                                    eps1, eps2, p, out);
    f_out<<<784, 256, 0, stream>>>(row_ptr, csr_src, p, out);
}

// Round 9
// 302.152 us; speedup vs baseline: 2.3057x; 2.3057x over previous
//
#include <hip/hip_runtime.h>

#define N_NODES 50000
#define N_EDGES 800000
#define IN_DIM 128
#define HID_DIM 256
#define OUT_DIM 2

typedef __attribute__((ext_vector_type(8))) short bh8;     // 8 bf16 (A/B frag)
typedef __attribute__((ext_vector_type(4))) float f4;      // C/D frag
typedef __attribute__((ext_vector_type(4))) unsigned u4;   // dwordx4

__device__ inline unsigned bf16rne(float f) {
    unsigned u = __float_as_uint(f);
    return (u + 0x7fffu + ((u >> 16) & 1u)) >> 16;
}

// ---------------------------------------------------------------------------
// k_prep_hist: x->bf16x2 + W1->B-frag pack + in-degree histogram (independent
// jobs, grid-strided). deg/desc pre-zeroed by the stream-ordered memset.
// ---------------------------------------------------------------------------
__global__ __launch_bounds__(256) void k_prep_hist(
    const float* __restrict__ x, const float* __restrict__ W1,
    const int* __restrict__ ei,
    unsigned* __restrict__ xb, unsigned* __restrict__ W1p,
    int* __restrict__ deg)
{
    const int gtid = blockIdx.x * 256 + threadIdx.x;
    const int gsz  = gridDim.x * 256;
    for (int i = gtid; i < 3200000; i += gsz) {       // all of x (3.2M float2)
        float2 v = ((const float2*)x)[i];
        xb[i] = (bf16rne(v.y) << 16) | bf16rne(v.x);
    }
    if (gtid < 16384) {                               // W1 -> B-frag pack
        int j = gtid;
        int d = j & 3, l = (j >> 2) & 63, s = (j >> 8) & 3, t = j >> 10;
        int k = 32 * s + 8 * (l >> 4) + 2 * d;
        int n = 16 * t + (l & 15);
        W1p[j] = (bf16rne(W1[(size_t)(k + 1) * HID_DIM + n]) << 16)
               |  bf16rne(W1[(size_t)k * HID_DIM + n]);
    }
    for (int e = gtid; e < N_EDGES; e += gsz)
        atomicAdd(&deg[ei[N_EDGES + e]], 1);
}

// ---------------------------------------------------------------------------
// k_scan: single-pass decoupled-lookback exclusive scan (verified in R6).
// ---------------------------------------------------------------------------
__global__ __launch_bounds__(256) void k_scan(
    const int* __restrict__ deg, unsigned long long* __restrict__ desc,
    int* __restrict__ row_ptr, int* __restrict__ cursor)
{
    __shared__ int wsum[4];
    __shared__ int s_prefix;
    const int tid = threadIdx.x, lane = tid & 63, wv = tid >> 6;
    const int b = blockIdx.x;
    int i = b * 256 + tid;
    int v = (i < N_NODES) ? deg[i] : 0;
    int s = v;
#pragma unroll
    for (int off = 1; off < 64; off <<= 1) {
        int t = __shfl_up(s, off, 64);
        if (lane >= off) s += t;
    }
    if (lane == 63) wsum[wv] = s;
    __syncthreads();
    int wexcl = 0;
    for (int w = 0; w < wv; w++) wexcl += wsum[w];
    int aggregate = wsum[0] + wsum[1] + wsum[2] + wsum[3];

    if (tid == 0) {
        if (b == 0) {
            atomicExch(&desc[0], (2ULL << 32) | (unsigned)aggregate);
            s_prefix = 0;
        } else {
            atomicExch(&desc[b], (1ULL << 32) | (unsigned)aggregate);
            int prefix = 0;
            int pb = b - 1;
            while (true) {
                unsigned long long st = atomicAdd(&desc[pb], 0ULL);
                unsigned flag = (unsigned)(st >> 32);
                if (flag == 0u) continue;
                prefix += (int)(unsigned)st;
                if (flag == 2u) break;
                pb--;
            }
            atomicExch(&desc[b], (2ULL << 32) | (unsigned)(prefix + aggregate));
            s_prefix = prefix;
        }
    }
    __syncthreads();
    int r = s_prefix + wexcl + s - v;
    if (i < N_NODES) { row_ptr[i] = r; cursor[i] = r; }
    if (b == gridDim.x - 1 && tid == 255) row_ptr[N_NODES] = s_prefix + aggregate;
}

// ---------------------------------------------------------------------------
// k_reorder: bucket src by dst
// ---------------------------------------------------------------------------
__global__ __launch_bounds__(256) void k_reorder(const int* __restrict__ ei,
                                                 int* __restrict__ cursor,
                                                 int* __restrict__ csr_src)
{
    int e = blockIdx.x * 256 + threadIdx.x;
    if (e < N_EDGES) {
        int dst = ei[N_EDGES + e];
        int pos = atomicAdd(&cursor[dst], 1);
        csr_src[pos] = ei[e];
    }
}

// ---------------------------------------------------------------------------
// k_gin1: per-wave 16-node tile (wave-private, no barriers).
// Phase A (new): 4-neighbor dwordx4 gather. lane = ns*16 + dq:
//   ns = neighbor subgroup (0..3), dq = dword-quad -> dwords [4dq..4dq+3]
//   each uint4 load covers cols [8dq..8dq+7] of one neighbor row; a batch of
//   8 loads keeps 32 neighbor rows (8 KB) in flight per wave. After the row
//   loop, shfl-xor over lane bits 4,5 sums the 4 subgroups; ns==0 lanes add
//   the (1+e1)x self term and ds_write_b128 the bf16-packed z row.
// Phase B/C: MFMA GEMM1 + epilogue, byte-identical to R6 (verified).
// ---------------------------------------------------------------------------
__global__ __launch_bounds__(256) void k_gin1(
    const float* __restrict__ x, const unsigned* __restrict__ xb,
    const int* __restrict__ row_ptr, const int* __restrict__ csr_src,
    const unsigned* __restrict__ W1p, const float* __restrict__ b1,
    const float* __restrict__ W2, const float* __restrict__ b2,
    const float* __restrict__ eps1p, const float* __restrict__ eps2p,
    float* __restrict__ p, float* __restrict__ out)
{
    __shared__ unsigned z16[4][16 * 68];
    const int tid = threadIdx.x, lane = tid & 63, wv = tid >> 6;
    const int wu = blockIdx.x * 4 + wv;
    if (wu >= 3125) return;                       // 3125*16 == N_NODES
    const int node0 = wu * 16;
    const float e1 = 1.0f + eps1p[0];
    const int ns = lane >> 4;                     // neighbor subgroup 0..3
    const int dq = lane & 15;                     // dword quad 0..15

    // ---- Phase A ----
    for (int nn = 0; nn < 16; nn++) {
        int node = node0 + nn;
        float ax[4] = {0.f, 0.f, 0.f, 0.f};
        float ay[4] = {0.f, 0.f, 0.f, 0.f};
        int beg = row_ptr[node], end = row_ptr[node + 1];
        for (int bb = beg; bb < end; bb += 64) {
            int cnt = min(64, end - bb);
            int srcs = csr_src[bb + min(lane, cnt - 1)];
            int G = (cnt + 3) >> 2;               // groups of 4 neighbors
            for (int g0 = 0; g0 < G; g0 += 8) {
                int gg = min(8, G - g0);          // wave-uniform
                u4 u[8];
#pragma unroll
                for (int g = 0; g < 8; g++) {
                    if (g < gg) {
                        int idx = 4 * (g0 + g) + ns;
                        int sq = __shfl(srcs, min(idx, cnt - 1), 64);
                        u[g] = *(const u4*)(xb + (size_t)sq * 64 + 4 * dq);
                    }
                }
#pragma unroll
                for (int g = 0; g < 8; g++) {
                    if (g < gg) {
                        int idx = 4 * (g0 + g) + ns;
                        float m = (idx < cnt) ? 1.f : 0.f;
#pragma unroll
                        for (int d = 0; d < 4; d++) {
                            ax[d] = fmaf(m, __uint_as_float(u[g][d] << 16), ax[d]);
                            ay[d] = fmaf(m, __uint_as_float(u[g][d] & 0xffff0000u), ay[d]);
                        }
                    }
                }
            }
        }
        // reduce the 4 neighbor subgroups (lane bits 4 and 5)
#pragma unroll
        for (int off = 16; off <= 32; off <<= 1) {
#pragma unroll
            for (int d = 0; d < 4; d++) {
                ax[d] += __shfl_xor(ax[d], off, 64);
                ay[d] += __shfl_xor(ay[d], off, 64);
            }
        }
        if (ns == 0) {                            // 16 lanes: self term + write
            const float* xr = x + (size_t)node * IN_DIM + 8 * dq;
            float4 x0 = *(const float4*)xr;
            float4 x1 = *(const float4*)(xr + 4);
            ax[0] = fmaf(e1, x0.x, ax[0]); ay[0] = fmaf(e1, x0.y, ay[0]);
            ax[1] = fmaf(e1, x0.z, ax[1]); ay[1] = fmaf(e1, x0.w, ay[1]);
            ax[2] = fmaf(e1, x1.x, ax[2]); ay[2] = fmaf(e1, x1.y, ay[2]);
            ax[3] = fmaf(e1, x1.z, ax[3]); ay[3] = fmaf(e1, x1.w, ay[3]);
            u4 w;
#pragma unroll
            for (int d = 0; d < 4; d++)
                w[d] = (bf16rne(ay[d]) << 16) | bf16rne(ax[d]);
            *(u4*)&z16[wv][nn * 68 + 4 * dq] = w;
        }
    }
    // wave-private: no __syncthreads

    // ---- Phase B: MFMA GEMM1 (verified R6) ----
    const int q = lane >> 4, c = lane & 15;
    bh8 afrag[4];
#pragma unroll
    for (int s = 0; s < 4; s++)
        afrag[s] = *(const bh8*)&z16[wv][c * 68 + 16 * s + 4 * q];

    f4 acc[16];
#pragma unroll
    for (int t = 0; t < 16; t++) acc[t] = (f4){0.f, 0.f, 0.f, 0.f};
#pragma unroll
    for (int t = 0; t < 16; t++) {
#pragma unroll
        for (int s = 0; s < 4; s++) {
            bh8 bfrag = *(const bh8*)(W1p + ((size_t)(t * 4 + s) * 64 + lane) * 4);
            acc[t] = __builtin_amdgcn_mfma_f32_16x16x32_bf16(afrag[s], bfrag, acc[t], 0, 0, 0);
        }
    }

    // ---- Phase C: bias + ReLU + W2 + butterfly + store (verified R6) ----
    const float e2 = 1.0f + eps2p[0];
    float pxr[4] = {0.f, 0.f, 0.f, 0.f};
    float pyr[4] = {0.f, 0.f, 0.f, 0.f};
#pragma unroll
    for (int t = 0; t < 16; t++) {
        int n = 16 * t + c;
        float bb = b1[n];
        float2 w2 = *(const float2*)(W2 + (size_t)n * OUT_DIM);
#pragma unroll
        for (int r = 0; r < 4; r++) {
            float h = fmaxf(acc[t][r] + bb, 0.f);
            pxr[r] = fmaf(h, w2.x, pxr[r]);
            pyr[r] = fmaf(h, w2.y, pyr[r]);
        }
    }
#pragma unroll
    for (int off = 1; off < 16; off <<= 1) {
#pragma unroll
        for (int r = 0; r < 4; r++) {
            pxr[r] += __shfl_xor(pxr[r], off, 64);
            pyr[r] += __shfl_xor(pyr[r], off, 64);
        }
    }
    if (c == 0) {
        float2 b2v = *(const float2*)b2;
#pragma unroll
        for (int r = 0; r < 4; r++) {
            int node = node0 + q * 4 + r;
            *(float2*)(p + (size_t)node * OUT_DIM) = make_float2(pxr[r], pyr[r]);
            float2 o;
            o.x = fmaf(e2, pxr[r], b2v.x);
            o.y = fmaf(e2, pyr[r], b2v.y);
            *(float2*)(out + (size_t)node * OUT_DIM) = o;
        }
    }
}

// ---------------------------------------------------------------------------
// k_out: out[n] += sum_{src in row n} p[src]  (p is 400 KB -> L2-hot gather)
// ---------------------------------------------------------------------------
__global__ __launch_bounds__(256) void k_out(
    const int* __restrict__ row_ptr, const int* __restrict__ csr_src,
    const float* __restrict__ p, float* __restrict__ out)
{
    const int tid = threadIdx.x, lane = tid & 63, wv = tid >> 6;
    const int node = blockIdx.x * 32 + wv * 8 + (lane >> 3);
    const int l = lane & 7;
    float sx = 0.f, sy = 0.f;
    if (node < N_NODES) {
        int beg = row_ptr[node], end = row_ptr[node + 1];
        for (int j = beg + l; j < end; j += 8) {
            int src = csr_src[j];
            float2 v = *(const float2*)(p + (size_t)src * OUT_DIM);
            sx += v.x; sy += v.y;
        }
    }
#pragma unroll
    for (int off = 1; off <= 4; off <<= 1) {
        sx += __shfl_xor(sx, off, 64);
        sy += __shfl_xor(sy, off, 64);
    }
    if (l == 0 && node < N_NODES) {
        float2 o = *(const float2*)(out + (size_t)node * OUT_DIM);
        o.x += sx; o.y += sy;
        *(float2*)(out + (size_t)node * OUT_DIM) = o;
    }
}

extern "C" void kernel_launch(void* const* d_in, const int* in_sizes, int n_in,
                              void* d_out, int out_size, void* d_ws, size_t ws_size,
                              hipStream_t stream)
{
    (void)in_sizes; (void)n_in; (void)out_size; (void)ws_size;
    const float* x    = (const float*)d_in[0];
    const int*   ei   = (const int*)d_in[1];
    const float* W1   = (const float*)d_in[2];
    const float* b1   = (const float*)d_in[3];
    const float* W2   = (const float*)d_in[4];
    const float* b2   = (const float*)d_in[5];
    const float* eps1 = (const float*)d_in[6];
    const float* eps2 = (const float*)d_in[7];
    float* out = (float*)d_out;

    // workspace layout (deg and desc contiguous -> one memset)
    int* deg                 = (int*)d_ws;                          // 50048
    unsigned long long* desc = (unsigned long long*)(deg + 50048);  // 256
    int* row_ptr             = (int*)(desc + 256);                  // 50056
    int* cursor              = row_ptr + 50056;                     // 50048
    int* csr_src             = cursor + 50048;                      // 800000
    float* p                 = (float*)(csr_src + 800000);          // 100000
    unsigned* xb             = (unsigned*)(p + 100000);             // 3200000
    unsigned* W1p            = xb + 3200000;                        // 16384

    hipMemsetAsync(deg, 0, 50048 * sizeof(int) + 256 * sizeof(unsigned long long),
                   stream);
    k_prep_hist<<<784, 256, 0, stream>>>(x, W1, ei, xb, W1p, deg);
    k_scan<<<196, 256, 0, stream>>>(deg, desc, row_ptr, cursor);
    k_reorder<<<(N_EDGES + 255) / 256, 256, 0, stream>>>(ei, cursor, csr_src);
    k_gin1<<<782, 256, 0, stream>>>(x, xb, row_ptr, csr_src, W1p, b1, W2, b2,
                                    eps1, eps2, p, out);
    k_out<<<(N_NODES + 31) / 32, 256, 0, stream>>>(row_ptr, csr_src, p, out);
}

// Round 10
// 255.232 us; speedup vs baseline: 2.7296x; 1.1838x over previous
//
#include <hip/hip_runtime.h>

#define N_NODES 50000
#define N_EDGES 800000
#define IN_DIM 128
#define HID_DIM 256
#define OUT_DIM 2

typedef __attribute__((ext_vector_type(8))) short bh8;     // 8 bf16 (A/B frag)
typedef __attribute__((ext_vector_type(4))) float f4;      // C/D frag

__device__ inline unsigned bf16rne(float f) {
    unsigned u = __float_as_uint(f);
    return (u + 0x7fffu + ((u >> 16) & 1u)) >> 16;
}

// ---------------------------------------------------------------------------
// k_prep_hist: x->bf16x2 + W1->B-frag pack + in-degree histogram (independent
// jobs, grid-strided). deg/desc pre-zeroed by the stream-ordered memset.
// ---------------------------------------------------------------------------
__global__ __launch_bounds__(256) void k_prep_hist(
    const float* __restrict__ x, const float* __restrict__ W1,
    const int* __restrict__ ei,
    unsigned* __restrict__ xb, unsigned* __restrict__ W1p,
    int* __restrict__ deg)
{
    const int gtid = blockIdx.x * 256 + threadIdx.x;
    const int gsz  = gridDim.x * 256;
    for (int i = gtid; i < 3200000; i += gsz) {       // all of x (3.2M float2)
        float2 v = ((const float2*)x)[i];
        xb[i] = (bf16rne(v.y) << 16) | bf16rne(v.x);
    }
    if (gtid < 16384) {                               // W1 -> B-frag pack
        int j = gtid;
        int d = j & 3, l = (j >> 2) & 63, s = (j >> 8) & 3, t = j >> 10;
        int k = 32 * s + 8 * (l >> 4) + 2 * d;
        int n = 16 * t + (l & 15);
        W1p[j] = (bf16rne(W1[(size_t)(k + 1) * HID_DIM + n]) << 16)
               |  bf16rne(W1[(size_t)k * HID_DIM + n]);
    }
    for (int e = gtid; e < N_EDGES; e += gsz)
        atomicAdd(&deg[ei[N_EDGES + e]], 1);
}

// ---------------------------------------------------------------------------
// k_scan: single-pass decoupled-lookback exclusive scan (verified R6/R9).
// ---------------------------------------------------------------------------
__global__ __launch_bounds__(256) void k_scan(
    const int* __restrict__ deg, unsigned long long* __restrict__ desc,
    int* __restrict__ row_ptr, int* __restrict__ cursor)
{
    __shared__ int wsum[4];
    __shared__ int s_prefix;
    const int tid = threadIdx.x, lane = tid & 63, wv = tid >> 6;
    const int b = blockIdx.x;
    int i = b * 256 + tid;
    int v = (i < N_NODES) ? deg[i] : 0;
    int s = v;
#pragma unroll
    for (int off = 1; off < 64; off <<= 1) {
        int t = __shfl_up(s, off, 64);
        if (lane >= off) s += t;
    }
    if (lane == 63) wsum[wv] = s;
    __syncthreads();
    int wexcl = 0;
    for (int w = 0; w < wv; w++) wexcl += wsum[w];
    int aggregate = wsum[0] + wsum[1] + wsum[2] + wsum[3];

    if (tid == 0) {
        if (b == 0) {
            atomicExch(&desc[0], (2ULL << 32) | (unsigned)aggregate);
            s_prefix = 0;
        } else {
            atomicExch(&desc[b], (1ULL << 32) | (unsigned)aggregate);
            int prefix = 0;
            int pb = b - 1;
            while (true) {
                unsigned long long st = atomicAdd(&desc[pb], 0ULL);
                unsigned flag = (unsigned)(st >> 32);
                if (flag == 0u) continue;
                prefix += (int)(unsigned)st;
                if (flag == 2u) break;
                pb--;
            }
            atomicExch(&desc[b], (2ULL << 32) | (unsigned)(prefix + aggregate));
            s_prefix = prefix;
        }
    }
    __syncthreads();
    int r = s_prefix + wexcl + s - v;
    if (i < N_NODES) { row_ptr[i] = r; cursor[i] = r; }
    if (b == gridDim.x - 1 && tid == 255) row_ptr[N_NODES] = s_prefix + aggregate;
}

// ---------------------------------------------------------------------------
// k_reorder: bucket src by dst
// ---------------------------------------------------------------------------
__global__ __launch_bounds__(256) void k_reorder(const int* __restrict__ ei,
                                                 int* __restrict__ cursor,
                                                 int* __restrict__ csr_src)
{
    int e = blockIdx.x * 256 + threadIdx.x;
    if (e < N_EDGES) {
        int dst = ei[N_EDGES + e];
        int pos = atomicAdd(&cursor[dst], 1);
        csr_src[pos] = ei[e];
    }
}

// ---------------------------------------------------------------------------
// k_gin1 (R10): 32-node block, occupancy-doubled for the latency-bound gather.
//  - All 4 waves gather 8 nodes each (R6-verified dword gather, 16 loads in
//    flight) into shared z[32][68] (bf16-packed).
//  - __syncthreads, then waves 0/1 run the verified 16x16 MFMA tile + epilogue
//    (tile 0 = nodes node0..+16, tile 1 = +16..+32); waves 2/3 exit, freeing
//    wave slots for other blocks' gather phases.
//  - grid 1563 blocks -> ~24 waves/CU resident (vs 12 in R6/R9).
// ---------------------------------------------------------------------------
__global__ __launch_bounds__(256, 6) void k_gin1(
    const float* __restrict__ x, const unsigned* __restrict__ xb,
    const int* __restrict__ row_ptr, const int* __restrict__ csr_src,
    const unsigned* __restrict__ W1p, const float* __restrict__ b1,
    const float* __restrict__ W2, const float* __restrict__ b2,
    const float* __restrict__ eps1p, const float* __restrict__ eps2p,
    float* __restrict__ p, float* __restrict__ out)
{
    __shared__ unsigned z[32 * 68];                 // 8704 B
    const int tid = threadIdx.x, lane = tid & 63, wv = tid >> 6;
    const int node0 = blockIdx.x * 32;
    const float e1 = 1.0f + eps1p[0];

    // ---- Phase A: gather (8 nodes per wave) ----
    for (int nn = 0; nn < 8; nn++) {
        int node = node0 + 8 * wv + nn;
        float ax = 0.f, ay = 0.f;
        if (node < N_NODES) {
            int beg = row_ptr[node], end = row_ptr[node + 1];
            for (int bb = beg; bb < end; bb += 64) {
                int cnt = min(64, end - bb);
                int srcs = csr_src[bb + ((lane < cnt) ? lane : 0)];
                for (int j0 = 0; j0 < cnt; j0 += 16) {
                    unsigned u[16];
#pragma unroll
                    for (int g = 0; g < 16; g++) {
                        int idx = j0 + g;
                        int sq = __shfl(srcs, (idx < cnt) ? idx : 0, 64);
                        u[g] = xb[(size_t)sq * 64 + lane];
                    }
#pragma unroll
                    for (int g = 0; g < 16; g++) {
                        if (j0 + g < cnt) {
                            ax += __uint_as_float(u[g] << 16);
                            ay += __uint_as_float(u[g] & 0xffff0000u);
                        }
                    }
                }
            }
            float2 xv = *(const float2*)(x + (size_t)node * IN_DIM + 2 * lane);
            ax = fmaf(e1, xv.x, ax);
            ay = fmaf(e1, xv.y, ay);
        }
        z[(8 * wv + nn) * 68 + lane] = (bf16rne(ay) << 16) | bf16rne(ax);
    }
    __syncthreads();
    if (wv >= 2) return;                            // free wave slots

    // ---- Phase B: MFMA GEMM1 (verified R6) — wave wv owns tile wv ----
    const int q = lane >> 4, c = lane & 15;
    unsigned* zt = &z[(16 * wv) * 68];
    bh8 afrag[4];
#pragma unroll
    for (int s = 0; s < 4; s++)
        afrag[s] = *(const bh8*)&zt[c * 68 + 16 * s + 4 * q];

    f4 acc[16];
#pragma unroll
    for (int t = 0; t < 16; t++) acc[t] = (f4){0.f, 0.f, 0.f, 0.f};
#pragma unroll
    for (int t = 0; t < 16; t++) {
#pragma unroll
        for (int s = 0; s < 4; s++) {
            bh8 bfrag = *(const bh8*)(W1p + ((size_t)(t * 4 + s) * 64 + lane) * 4);
            acc[t] = __builtin_amdgcn_mfma_f32_16x16x32_bf16(afrag[s], bfrag, acc[t], 0, 0, 0);
        }
    }

    // ---- Phase C: bias + ReLU + W2 + butterfly + store (verified R6) ----
    const float e2 = 1.0f + eps2p[0];
    float pxr[4] = {0.f, 0.f, 0.f, 0.f};
    float pyr[4] = {0.f, 0.f, 0.f, 0.f};
#pragma unroll
    for (int t = 0; t < 16; t++) {
        int n = 16 * t + c;
        float bb = b1[n];
        float2 w2 = *(const float2*)(W2 + (size_t)n * OUT_DIM);
#pragma unroll
        for (int r = 0; r < 4; r++) {
            float h = fmaxf(acc[t][r] + bb, 0.f);
            pxr[r] = fmaf(h, w2.x, pxr[r]);
            pyr[r] = fmaf(h, w2.y, pyr[r]);
        }
    }
#pragma unroll
    for (int off = 1; off < 16; off <<= 1) {
#pragma unroll
        for (int r = 0; r < 4; r++) {
            pxr[r] += __shfl_xor(pxr[r], off, 64);
            pyr[r] += __shfl_xor(pyr[r], off, 64);
        }
    }
    if (c == 0) {
        float2 b2v = *(const float2*)b2;
#pragma unroll
        for (int r = 0; r < 4; r++) {
            int node = node0 + 16 * wv + q * 4 + r;
            if (node < N_NODES) {
                *(float2*)(p + (size_t)node * OUT_DIM) = make_float2(pxr[r], pyr[r]);
                float2 o;
                o.x = fmaf(e2, pxr[r], b2v.x);
                o.y = fmaf(e2, pyr[r], b2v.y);
                *(float2*)(out + (size_t)node * OUT_DIM) = o;
            }
        }
    }
}

// ---------------------------------------------------------------------------
// k_out: out[n] += sum_{src in row n} p[src]  (p is 400 KB -> L2/L3-hot)
// ---------------------------------------------------------------------------
__global__ __launch_bounds__(256) void k_out(
    const int* __restrict__ row_ptr, const int* __restrict__ csr_src,
    const float* __restrict__ p, float* __restrict__ out)
{
    const int tid = threadIdx.x, lane = tid & 63, wv = tid >> 6;
    const int node = blockIdx.x * 32 + wv * 8 + (lane >> 3);
    const int l = lane & 7;
    float sx = 0.f, sy = 0.f;
    if (node < N_NODES) {
        int beg = row_ptr[node], end = row_ptr[node + 1];
        for (int j = beg + l; j < end; j += 8) {
            int src = csr_src[j];
            float2 v = *(const float2*)(p + (size_t)src * OUT_DIM);
            sx += v.x; sy += v.y;
        }
    }
#pragma unroll
    for (int off = 1; off <= 4; off <<= 1) {
        sx += __shfl_xor(sx, off, 64);
        sy += __shfl_xor(sy, off, 64);
    }
    if (l == 0 && node < N_NODES) {
        float2 o = *(const float2*)(out + (size_t)node * OUT_DIM);
        o.x += sx; o.y += sy;
        *(float2*)(out + (size_t)node * OUT_DIM) = o;
    }
}

extern "C" void kernel_launch(void* const* d_in, const int* in_sizes, int n_in,
                              void* d_out, int out_size, void* d_ws, size_t ws_size,
                              hipStream_t stream)
{
    (void)in_sizes; (void)n_in; (void)out_size; (void)ws_size;
    const float* x    = (const float*)d_in[0];
    const int*   ei   = (const int*)d_in[1];
    const float* W1   = (const float*)d_in[2];
    const float* b1   = (const float*)d_in[3];
    const float* W2   = (const float*)d_in[4];
    const float* b2   = (const float*)d_in[5];
    const float* eps1 = (const float*)d_in[6];
    const float* eps2 = (const float*)d_in[7];
    float* out = (float*)d_out;

    // workspace layout (deg and desc contiguous -> one memset)
    int* deg                 = (int*)d_ws;                          // 50048
    unsigned long long* desc = (unsigned long long*)(deg + 50048);  // 256
    int* row_ptr             = (int*)(desc + 256);                  // 50056
    int* cursor              = row_ptr + 50056;                     // 50048
    int* csr_src             = cursor + 50048;                      // 800000
    float* p                 = (float*)(csr_src + 800000);          // 100000
    unsigned* xb             = (unsigned*)(p + 100000);             // 3200000
    unsigned* W1p            = xb + 3200000;                        // 16384

    hipMemsetAsync(deg, 0, 50048 * sizeof(int) + 256 * sizeof(unsigned long long),
                   stream);
    k_prep_hist<<<784, 256, 0, stream>>>(x, W1, ei, xb, W1p, deg);
    k_scan<<<196, 256, 0, stream>>>(deg, desc, row_ptr, cursor);
    k_reorder<<<(N_EDGES + 255) / 256, 256, 0, stream>>>(ei, cursor, csr_src);
    k_gin1<<<(N_NODES + 31) / 32, 256, 0, stream>>>(x, xb, row_ptr, csr_src,
                                                    W1p, b1, W2, b2,
                                                    eps1, eps2, p, out);
    k_out<<<(N_NODES + 31) / 32, 256, 0, stream>>>(row_ptr, csr_src, p, out);
}